// Round 7
// baseline (979.643 us; speedup 1.0000x reference)
//
#include <hip/hip_runtime.h>

// Decision-tree traversal — fused kernel, software-pipelined coalesced pack.
//
// x:      [N, W] int32 in {0,1}  (N=250000, W=784 -> 784 MB)
// choices:[N_NODES=65537] int32 split feature per node (values < 784)
// preds:  [N_NODES] float32 leaf prediction (0.0/1.0)
// depth:  scalar int32 on device (=15)
// out:    [N] int32 (bool 0/1)
//
// Attribution (kernel-only = dur_us - ~490us ws-poison fill in the timed
// window): R5 (per-thread pack) 522 vs R6 (coalesced pack) 488 -> the pack
// read pattern was worth only ~35us; a ~350-390us term is COMMON to every
// structure since R2. Leading theory: duty-cycle serialization — each wave
// alternates {issue loads} -> {vmcnt drain at first ballot} -> {long
// ALU/store phase, zero bytes in flight}, so average outstanding reads/CU
// collapse and read BW caps ~1.6 TB/s while the write-only poison fill
// (no consume-wait) streams 6.35 TB/s in the same window.
// Fix: explicit 2-stage software pipeline — rows r+2,r+3 loads are in
// flight while rows r,r+1 are balloted/stored. Bit layout, LDS layout and
// traverse are identical to R6 (verified absmax=0).

#define WPR 28   // 24 full words + 4 tail words per row

struct RowRegs { int4 p0, p1, p2, p3; };

__device__ __forceinline__ void load_row(RowRegs& R, const int* __restrict__ x,
                                         long long gr, int lane) {
    const int4* __restrict__ rp = (const int4*)(x + gr * 784LL);  // 16B-aligned
    R.p0 = rp[lane];                // features 4*lane+c        (1KB coalesced)
    R.p1 = rp[64 + lane];
    R.p2 = rp[128 + lane];
    R.p3 = rp[192 + (lane & 3)];    // tail: one 64B line
}

__device__ __forceinline__ void process_row(const RowRegs& R,
                                            unsigned* __restrict__ bits,
                                            int col, int lane) {
    unsigned long long m[12], t[4];             // fully unrolled -> static idx
    #pragma unroll
    for (int cmp = 0; cmp < 4; ++cmp) {
        m[0 + cmp] = __ballot(((&R.p0.x)[cmp] & 1) != 0);
        m[4 + cmp] = __ballot(((&R.p1.x)[cmp] & 1) != 0);
        m[8 + cmp] = __ballot(((&R.p2.x)[cmp] & 1) != 0);
        t[cmp]     = __ballot(((&R.p3.x)[cmp] & 1) != 0);
    }
    if (lane < 2) {                             // 2 lanes store the halves
        #pragma unroll
        for (int q = 0; q < 12; ++q) {
            const int w = ((q >> 2) << 3) + ((q & 3) << 1) + lane;
            bits[w * 256 + col] = (unsigned)(m[q] >> (lane << 5));
        }
    }
    if (lane == 0) {
        #pragma unroll
        for (int cmp = 0; cmp < 4; ++cmp)
            bits[(24 + cmp) * 256 + col] = (unsigned)t[cmp];
    }
}

__global__ __launch_bounds__(256) void fused_kernel(
    const int*   __restrict__ x,
    const int*   __restrict__ choices,
    const float* __restrict__ preds,
    const int*   __restrict__ depth_p,
    int*         __restrict__ out,
    int n)
{
    __shared__ unsigned bits[WPR * 256];   // [word][col]; bank = col&31, free

    const int tid  = threadIdx.x;
    const int lane = tid & 63;
    const int wid  = tid >> 6;
    const long long base = (long long)blockIdx.x * 256;
    const int wr0  = wid << 6;                       // wave's first local row

    auto graddr = [&](int r) -> long long {          // wave-uniform (SALU)
        const long long g = base + wr0 + r;
        return (g < n) ? g : (long long)(n - 1);
    };

    // ---- pack 64 rows, 2-row double-buffered pipeline (loads always in
    //      flight behind the ballot/store phase) ----
    RowRegs A0, A1, B0, B1;
    load_row(A0, x, graddr(0), lane);
    load_row(A1, x, graddr(1), lane);

    #pragma unroll 1
    for (int s = 0; s < 16; ++s) {
        const int r = s << 2;                        // rows r..r+3 this iter
        load_row(B0, x, graddr(r + 2), lane);        // prefetch while A busy
        load_row(B1, x, graddr(r + 3), lane);
        process_row(A0, bits, wr0 + r,     lane);
        process_row(A1, bits, wr0 + r + 1, lane);
        if (s < 15) {
            load_row(A0, x, graddr(r + 4), lane);    // prefetch while B busy
            load_row(A1, x, graddr(r + 5), lane);
        }
        process_row(B0, bits, wr0 + r + 2, lane);
        process_row(B1, bits, wr0 + r + 3, lane);
    }
    // no __syncthreads: each wave traverses only columns it wrote itself

    // ---- traverse own row from LDS (identical to R6, verified) ----
    const long long i = base + tid;
    if (i >= n) return;

    const int depth = *depth_p;                      // uniform scalar (=15)
    int node = 0;
    for (int d = 0; d < depth; ++d) {
        const int c = choices[node];                 // 256 KB table, L2-hot
        int w;
        if (c < 768) w = ((c >> 8) << 3) | ((c & 3) << 1) | ((c >> 7) & 1);
        else         w = 24 | (c & 3);
        const unsigned wv = bits[w * 256 + tid];     // bank = tid&31, free
        node = (node << 1) + (int)((wv >> ((c >> 2) & 31)) & 1u) + 1;
    }
    out[i] = (preds[node] != 0.0f) ? 1 : 0;          // bool as int32
}

// ------------------------------------------------ fallback for generic w
__global__ __launch_bounds__(256) void direct_kernel(
    const int*   __restrict__ x,
    const int*   __restrict__ choices,
    const float* __restrict__ preds,
    const int*   __restrict__ depth_p,
    int*         __restrict__ out,
    int n, int w)
{
    const int i = blockIdx.x * blockDim.x + threadIdx.x;
    if (i >= n) return;
    const int depth = *depth_p;
    const int* __restrict__ row = x + (long long)i * (long long)w;
    int node = 0;
    for (int d = 0; d < depth; ++d) {
        const int c   = choices[node];
        const int bit = row[c];
        node = node * 2 + bit + 1;
    }
    out[i] = (preds[node] != 0.0f) ? 1 : 0;
}

extern "C" void kernel_launch(void* const* d_in, const int* in_sizes, int n_in,
                              void* d_out, int out_size, void* d_ws, size_t ws_size,
                              hipStream_t stream) {
    const int*   x       = (const int*)d_in[0];
    const int*   choices = (const int*)d_in[1];
    const float* preds   = (const float*)d_in[2];
    const int*   depth_p = (const int*)d_in[3];
    int*         out     = (int*)d_out;

    const int n = out_size;                 // 250000 samples
    const int w = in_sizes[0] / n;          // 784 features

    const int block = 256;
    const int grid  = (n + block - 1) / block;   // 977 blocks

    if (w == 784) {
        fused_kernel<<<grid, block, 0, stream>>>(x, choices, preds, depth_p,
                                                 out, n);
    } else {
        direct_kernel<<<grid, block, 0, stream>>>(x, choices, preds, depth_p,
                                                  out, n, w);
    }
}